// Round 4
// baseline (345.757 us; speedup 1.0000x reference)
//
#include <hip/hip_runtime.h>
#include <hip/hip_bf16.h>

// out[512, 65536] = inputs[512,256] @ features[65536,256]^T  (fp32 in/out)
//
// v5: latency-hiding fix for v4 (which was latency-bound: MfmaUtil 8%,
// VALUBusy 5%, HBM 26%, occ 21%).
//   - BN=64: Bs = 32 KB -> 4 blocks/CU, __launch_bounds__(256,4) -> 16 waves/CU
//     (2x v4's TLP). grid = 1024, all co-resident; B still read from HBM once.
//   - 4 waves stack in M (64 rows each) over the full 64-col panel; 2 m-passes.
//   - A fragments from global (L2-resident 256 KB ws) with EXPLICIT k+1
//     register prefetch (afc/afn double buffer) so the L2 latency hides under
//     the current step's ds_reads + MFMAs. No barriers in the main loop.

#define M_DIM 512
#define N_DIM 65536
#define K_DIM 256
#define BN 64
#define MP 256          // rows per m-pass (4 waves x 64)

typedef __bf16 bf16x8 __attribute__((ext_vector_type(8)));
typedef float f32x4 __attribute__((ext_vector_type(4)));

// ---- kernel 1: inputs [512][256] fp32 -> bf16 ws, row-major ----
__global__ __launch_bounds__(256) void cvt_inputs(const float* __restrict__ A,
                                                  __bf16* __restrict__ Aw) {
    const int t = blockIdx.x * 256 + threadIdx.x;   // 16384 threads x 8 elems
    const float* src = A + (size_t)t * 8;
    f32x4 v0 = *(const f32x4*)src;
    f32x4 v1 = *(const f32x4*)(src + 4);
    bf16x8 h;
    h[0] = (__bf16)v0[0]; h[1] = (__bf16)v0[1];
    h[2] = (__bf16)v0[2]; h[3] = (__bf16)v0[3];
    h[4] = (__bf16)v1[0]; h[5] = (__bf16)v1[1];
    h[6] = (__bf16)v1[2]; h[7] = (__bf16)v1[3];
    *(bf16x8*)(Aw + (size_t)t * 8) = h;
}

__global__ __launch_bounds__(256, 4) void hm_gemm_bt(
    const __bf16* __restrict__ Aw,  // [512][256] bf16 ws (L2-resident)
    const float*  __restrict__ B,   // features [65536][256] fp32
    float* __restrict__ C)          // out [512][65536] fp32
{
    __shared__ __align__(16) __bf16 Bs[BN * K_DIM];  // 32 KB, full-K B panel

    const int tid  = threadIdx.x;
    const int lane = tid & 63;
    const int wave = tid >> 6;            // 4 waves stacked in M
    const int wm   = wave * 64;

    const int n0 = blockIdx.x * BN;       // grid = 1024, one 64-col panel/block

    const int lrow = lane & 15;
    const int lk   = (lane >> 4) * 8;
    const int lx   = lrow & 7;            // XOR key for swizzled Bs reads

    // ---- stage B panel once: 64 rows x 256 k, fp32 -> bf16, swizzled
    #pragma unroll 4
    for (int it = 0; it < 8; ++it) {
        const int c   = it * 256 + tid;   // 0..2047 bf16x8 slots
        const int row = c >> 5;           // 0..63
        const int s   = c & 31;
        const float* src = B + (size_t)(n0 + row) * K_DIM + s * 8;
        f32x4 v0 = *(const f32x4*)(src);
        f32x4 v1 = *(const f32x4*)(src + 4);
        bf16x8 h;
        h[0] = (__bf16)v0[0]; h[1] = (__bf16)v0[1];
        h[2] = (__bf16)v0[2]; h[3] = (__bf16)v0[3];
        h[4] = (__bf16)v1[0]; h[5] = (__bf16)v1[1];
        h[6] = (__bf16)v1[2]; h[7] = (__bf16)v1[3];
        const int sst = s ^ (row & 7);
        *(bf16x8*)&Bs[row * K_DIM + sst * 8] = h;
    }
    __syncthreads();                      // Bs read-only after this: no more barriers

    for (int mp = 0; mp < M_DIM / MP; ++mp) {
        f32x4 acc[4][4];
        #pragma unroll
        for (int i = 0; i < 4; ++i)
            #pragma unroll
            for (int j = 0; j < 4; ++j)
                acc[i][j] = f32x4{0.f, 0.f, 0.f, 0.f};

        const __bf16* Ab = Aw + (size_t)(mp * MP + wm + lrow) * K_DIM + lk;

        // prologue: prefetch k=0 A fragments into registers
        bf16x8 afc[4], afn[4];
        #pragma unroll
        for (int i = 0; i < 4; ++i)
            afc[i] = *(const bf16x8*)(Ab + (size_t)(i * 16) * K_DIM);

        #pragma unroll
        for (int k = 0; k < K_DIM; k += 32) {
            // issue next step's A loads first (L2 latency hides under this step)
            if (k + 32 < K_DIM) {
                #pragma unroll
                for (int i = 0; i < 4; ++i)
                    afn[i] = *(const bf16x8*)(Ab + (size_t)(i * 16) * K_DIM
                                                 + (k + 32));
            }
            bf16x8 bfr[4];
            #pragma unroll
            for (int j = 0; j < 4; ++j) {
                const int row = j * 16 + lrow;
                const int pos = (((k + lk) >> 3) ^ lx);
                bfr[j] = *(const bf16x8*)&Bs[row * K_DIM + pos * 8];
            }
            #pragma unroll
            for (int i = 0; i < 4; ++i)
                #pragma unroll
                for (int j = 0; j < 4; ++j)
                    acc[i][j] = __builtin_amdgcn_mfma_f32_16x16x32_bf16(
                        bfr[j], afc[i], acc[i][j], 0, 0, 0);  // D.row -> n
            #pragma unroll
            for (int i = 0; i < 4; ++i)
                afc[i] = afn[i];
        }

        // ---- epilogue: lane holds C[m = ..+lane&15][n = j*16+(lane>>4)*4+0..3]
        const int lm = lane & 15;
        const int ln = (lane >> 4) * 4;
        #pragma unroll
        for (int i = 0; i < 4; ++i) {
            const size_t rowbase = (size_t)(mp * MP + wm + i * 16 + lm) * N_DIM;
            #pragma unroll
            for (int j = 0; j < 4; ++j) {
                float* dst = C + rowbase + (n0 + j * 16 + ln);
                *(f32x4*)dst = acc[i][j];
            }
        }
    }
}

extern "C" void kernel_launch(void* const* d_in, const int* in_sizes, int n_in,
                              void* d_out, int out_size, void* d_ws, size_t ws_size,
                              hipStream_t stream) {
    // setup_inputs order: inputs, indexes, features, mIoU, IoU
    const float* inputs   = (const float*)d_in[0];
    const float* features = (const float*)d_in[2];
    float* out = (float*)d_out;
    __bf16* Aw = (__bf16*)d_ws;          // 256 KB of workspace

    hipLaunchKernelGGL(cvt_inputs, dim3(M_DIM * K_DIM / (256 * 8)), dim3(256),
                       0, stream, inputs, Aw);

    hipLaunchKernelGGL(hm_gemm_bt, dim3(N_DIM / BN), dim3(256), 0, stream,
                       Aw, features, out);
}

// Round 6
// 211.865 us; speedup vs baseline: 1.6320x; 1.6320x over previous
//
#include <hip/hip_runtime.h>
#include <hip/hip_bf16.h>

// out[512, 65536] = inputs[512,256] @ features[65536,256]^T  (fp32 in/out)
//
// v7: v3's proven-correct sync (compiler-enforced vmcnt drain via one
// __syncthreads per k-step) + double-buffered per-wave As tiles so the
// tile t+1 DMA overlaps the whole step-t compute phase.
//   - B panel [64][256] fp32->bf16 staged ONCE (32 KB, XOR-swizzled).
//   - A from bf16 ws via global_load_lds; per-wave-private 64-row tiles,
//     swizzle folded into the per-lane DMA *source* address (rule #21).
//   - NO inline-asm waitcnt (v6 raced: counted vmcnt depends on scheduler
//     placement of gload_lds). __syncthreads' built-in vmcnt(0) drain is
//     placement-proof.
//   - nt loads for B (read-once), nt stores for C (write-once): keep L2 for A.

#define M_DIM 512
#define N_DIM 65536
#define K_DIM 256
#define BN 64

typedef __bf16 bf16x8 __attribute__((ext_vector_type(8)));
typedef float f32x4 __attribute__((ext_vector_type(4)));

// ---- kernel 1: inputs [512][256] fp32 -> bf16 ws, row-major ----
__global__ __launch_bounds__(256) void cvt_inputs(const float* __restrict__ A,
                                                  __bf16* __restrict__ Aw) {
    const int t = blockIdx.x * 256 + threadIdx.x;   // 16384 threads x 8 elems
    const float* src = A + (size_t)t * 8;
    f32x4 v0 = *(const f32x4*)src;
    f32x4 v1 = *(const f32x4*)(src + 4);
    bf16x8 h;
    h[0] = (__bf16)v0[0]; h[1] = (__bf16)v0[1];
    h[2] = (__bf16)v0[2]; h[3] = (__bf16)v0[3];
    h[4] = (__bf16)v1[0]; h[5] = (__bf16)v1[1];
    h[6] = (__bf16)v1[2]; h[7] = (__bf16)v1[3];
    *(bf16x8*)(Aw + (size_t)t * 8) = h;
}

static __device__ __forceinline__ void gload_lds16(const __bf16* g, __bf16* l) {
    __builtin_amdgcn_global_load_lds(
        (const __attribute__((address_space(1))) void*)g,
        (__attribute__((address_space(3))) void*)l, 16, 0, 0);
}

__global__ __launch_bounds__(256, 2) void hm_gemm_bt(
    const __bf16* __restrict__ Aw,  // [512][256] bf16 ws (L2-resident)
    const float*  __restrict__ B,   // features [65536][256] fp32
    float* __restrict__ C)          // out [512][65536] fp32
{
    __shared__ __align__(16) __bf16 Bs[BN * K_DIM];   // 32 KB, full-K B panel
    __shared__ __align__(16) __bf16 As[2][4][2048];   // 32 KB: [buf][wave][64r x 32k]

    const int tid  = threadIdx.x;
    const int lane = tid & 63;
    const int wave = tid >> 6;             // 4 waves stacked in M, 64 rows each
    const int n0   = blockIdx.x * BN;      // grid = 1024 panels

    const int lrow = lane & 15;
    const int lx   = lane & 7;             // Bs XOR key (row&7 == lane&7)

    // A-DMA per-lane source constants. Chunk c, lane l writes LDS elems
    // c*512 + l*8 -> row_local = c*16 + (l>>2), phys 16B slot l&3.
    // Stored logical slot must be (l&3) ^ (row&3) = (l&3) ^ ((l>>2)&3).
    const int lrow4   = lane >> 2;
    const int sslot   = (lane & 3) ^ (lrow4 & 3);
    const int laneAof = lrow4 * K_DIM + sslot * 8;    // elem offset in ws

    // As read: logical slot s = lane>>4 at row (row&3 == lane&3):
    // phys p = s ^ (row&3) -> lane-constant.
    const int pA = (lane >> 4) ^ (lane & 3);

    // ---- issue tile 0 DMA first: flies during the whole Bs staging phase
    {
        const __bf16* src = Aw + (size_t)(wave * 64) * K_DIM + laneAof;
        #pragma unroll
        for (int c = 0; c < 4; ++c)
            gload_lds16(src + (size_t)(c * 16) * K_DIM, &As[0][wave][c * 512]);
    }

    // ---- stage B panel once: 64 rows x 256 k, fp32 -> bf16, swizzled, NT loads
    #pragma unroll 4
    for (int it = 0; it < 8; ++it) {
        const int c   = it * 256 + tid;    // 0..2047 bf16x8 slots
        const int row = c >> 5;            // 0..63
        const int s   = c & 31;
        const f32x4* src = (const f32x4*)(B + (size_t)(n0 + row) * K_DIM + s * 8);
        f32x4 v0 = __builtin_nontemporal_load(src);
        f32x4 v1 = __builtin_nontemporal_load(src + 1);
        bf16x8 h;
        h[0] = (__bf16)v0[0]; h[1] = (__bf16)v0[1];
        h[2] = (__bf16)v0[2]; h[3] = (__bf16)v0[3];
        h[4] = (__bf16)v1[0]; h[5] = (__bf16)v1[1];
        h[6] = (__bf16)v1[2]; h[7] = (__bf16)v1[3];
        const int sst = s ^ (row & 7);
        *(bf16x8*)&Bs[row * K_DIM + sst * 8] = h;
    }

    __syncthreads();   // compiler drains vmcnt(0): Bs AND tile 0 are ready

    f32x4 acc[4][4];
    #pragma unroll
    for (int i = 0; i < 4; ++i)
        #pragma unroll
        for (int j = 0; j < 4; ++j)
            acc[i][j] = f32x4{0.f, 0.f, 0.f, 0.f};

    // ---- 16 k-steps: t -> (mp = t>>3, kb = t&7). One barrier per step.
    #pragma unroll
    for (int t = 0; t < 16; ++t) {
        // issue NEXT tile's DMA into the other buffer; it overlaps this
        // step's ds_reads + MFMAs and is drained by the end-of-step barrier.
        if (t < 15) {
            const int tn = t + 1;
            const __bf16* src = Aw
                + (size_t)((tn >> 3) * 256 + wave * 64) * K_DIM
                + (tn & 7) * 32 + laneAof;
            #pragma unroll
            for (int c = 0; c < 4; ++c)
                gload_lds16(src + (size_t)(c * 16) * K_DIM,
                            &As[tn & 1][wave][c * 512]);
        }

        const __bf16* at = &As[t & 1][wave][0];
        bf16x8 af[4], bfr[4];
        #pragma unroll
        for (int i = 0; i < 4; ++i)
            af[i] = *(const bf16x8*)(at + (i * 16 + lrow) * 32 + pA * 8);
        const int kb = t & 7;
        #pragma unroll
        for (int j = 0; j < 4; ++j) {
            const int row = j * 16 + lrow;
            const int pos = (kb * 4 + (lane >> 4)) ^ lx;
            bfr[j] = *(const bf16x8*)&Bs[row * K_DIM + pos * 8];
        }
        #pragma unroll
        for (int i = 0; i < 4; ++i)
            #pragma unroll
            for (int j = 0; j < 4; ++j)
                acc[i][j] = __builtin_amdgcn_mfma_f32_16x16x32_bf16(
                    bfr[j], af[i], acc[i][j], 0, 0, 0);   // swapped: D.row -> n

        // ---- per-mp epilogue at t=7 and t=15: NONTEMPORAL f32x4 stores
        if (t == 7 || t == 15) {
            const int mp = t >> 3;
            const int lm = lane & 15;
            const int ln = (lane >> 4) * 4;
            #pragma unroll
            for (int i = 0; i < 4; ++i) {
                const size_t rowbase =
                    (size_t)(mp * 256 + wave * 64 + i * 16 + lm) * N_DIM;
                #pragma unroll
                for (int j = 0; j < 4; ++j) {
                    f32x4* dst = (f32x4*)(C + rowbase + (n0 + j * 16 + ln));
                    __builtin_nontemporal_store(acc[i][j], dst);
                }
            }
            if (t == 7) {
                #pragma unroll
                for (int i = 0; i < 4; ++i)
                    #pragma unroll
                    for (int j = 0; j < 4; ++j)
                        acc[i][j] = f32x4{0.f, 0.f, 0.f, 0.f};
            }
        }

        // end-of-step barrier: compiler emits s_waitcnt vmcnt(0) before
        // s_barrier -> tile t+1 is fully landed; placement-proof correctness.
        if (t < 15) __syncthreads();
    }
}

extern "C" void kernel_launch(void* const* d_in, const int* in_sizes, int n_in,
                              void* d_out, int out_size, void* d_ws, size_t ws_size,
                              hipStream_t stream) {
    // setup_inputs order: inputs, indexes, features, mIoU, IoU
    const float* inputs   = (const float*)d_in[0];
    const float* features = (const float*)d_in[2];
    float* out = (float*)d_out;
    __bf16* Aw = (__bf16*)d_ws;          // 256 KB of workspace

    hipLaunchKernelGGL(cvt_inputs, dim3(M_DIM * K_DIM / (256 * 8)), dim3(256),
                       0, stream, inputs, Aw);

    hipLaunchKernelGGL(hm_gemm_bt, dim3(N_DIM / BN), dim3(256), 0, stream,
                       Aw, features, out);
}